// Round 11
// baseline (30.749 us; speedup 1.0000x reference)
//
#include <hip/hip_runtime.h>

// Problem constants
#define BB 4
#define LL 512
#define WW 256
#define EE 300
#define HH 768

typedef __attribute__((ext_vector_type(8))) short bf16x8;
typedef __attribute__((ext_vector_type(4))) float f32x4;

__device__ __forceinline__ short f2bf(float f) {
    union { float f; unsigned u; } v; v.f = f;
    unsigned r = (v.u + 0x7FFFu + ((v.u >> 16) & 1u)) >> 16;
    return (short)r;
}

// ---------------------------------------------------------------------------
// kA: aT = (emb_a[word_seq] @ lin_w + lin_b), bf16, k-major aT[b][h/8][w][h%8].
// (R8 body, unchanged. ~3.5-4us via R9 decomposition probe.)
// ---------------------------------------------------------------------------
__global__ __launch_bounds__(256, 1) void kA_a_gemm(
    const int*   __restrict__ word_seq,
    const float* __restrict__ emb_a,
    const float* __restrict__ lin_w,
    const float* __restrict__ lin_b,
    short*       __restrict__ aT)      // [4][96][256][8] bf16
{
    __shared__ short eaL[2][64 * 168];   // [half][m-row][k] bf16, stride 168
    __shared__ short lwL[2][64 * 168];   // [half][n-row(h)][k]

    const int t  = threadIdx.x;
    const int m0 = (blockIdx.x & 15) * 64;
    const int n0 = (blockIdx.x >> 4) * 64;

    const int lane = t & 63, wv = t >> 6;
    const int l15 = lane & 15, l4 = lane >> 4;

    const int r_ea = t >> 2;             // 0..63 m-row
    const int q_ea = t & 3;              // quarter of the 160-wide half
    const int h_lw = t & 63;             // n-row
    const int q_lw = t >> 6;             // quarter

    const int    wrow = word_seq[m0 + r_ea];
    const float* arow = emb_a + (long)wrow * EE;

    f32x4 acc[4] = {};
    float ea_reg[40], lw_reg[40];

#pragma unroll
    for (int half = 0; half < 2; ++half) {
        const int k0 = half * 160;
        // ---- issue this half's loads (all independent) ----
        {
            const int cbase = k0 + q_ea * 40;
#pragma unroll
            for (int c4 = 0; c4 < 10; ++c4) {
                const int col = cbase + c4 * 4;
                if (col <= 296) {        // full float4 real (E=300, col%4==0)
                    const float4 p = *(const float4*)(arow + col);
                    ea_reg[c4 * 4 + 0] = p.x; ea_reg[c4 * 4 + 1] = p.y;
                    ea_reg[c4 * 4 + 2] = p.z; ea_reg[c4 * 4 + 3] = p.w;
                } else {
                    ea_reg[c4 * 4 + 0] = 0.f; ea_reg[c4 * 4 + 1] = 0.f;
                    ea_reg[c4 * 4 + 2] = 0.f; ea_reg[c4 * 4 + 3] = 0.f;
                }
            }
            const int cb2 = k0 + q_lw * 40;
#pragma unroll
            for (int j = 0; j < 40; ++j) {
                const int col = cb2 + j;
                lw_reg[j] = (col < EE) ? lin_w[(long)col * HH + n0 + h_lw] : 0.f;
            }
        }
        // ---- pack to LDS ----
        {
            const int eoff = r_ea * 168 + q_ea * 40;
#pragma unroll
            for (int c8 = 0; c8 < 5; ++c8) {
                bf16x8 sv;
#pragma unroll
                for (int j = 0; j < 8; ++j) sv[j] = f2bf(ea_reg[c8 * 8 + j]);
                *(bf16x8*)(&eaL[half][eoff + c8 * 8]) = sv;
            }
            const int loff = h_lw * 168 + q_lw * 40;
#pragma unroll
            for (int c8 = 0; c8 < 5; ++c8) {
                bf16x8 sv;
#pragma unroll
                for (int j = 0; j < 8; ++j) sv[j] = f2bf(lw_reg[c8 * 8 + j]);
                *(bf16x8*)(&lwL[half][loff + c8 * 8]) = sv;
            }
        }
        __syncthreads();
        // ---- MFMA on this half (5 k-steps x 4 n-frags) ----
#pragma unroll
        for (int ks = 0; ks < 5; ++ks) {
            const bf16x8 af =
                *(const bf16x8*)(&eaL[half][(wv * 16 + l15) * 168 + ks * 32 + l4 * 8]);
#pragma unroll
            for (int nf = 0; nf < 4; ++nf) {
                const bf16x8 bfv =
                    *(const bf16x8*)(&lwL[half][(nf * 16 + l15) * 168 + ks * 32 + l4 * 8]);
                acc[nf] = __builtin_amdgcn_mfma_f32_16x16x32_bf16(af, bfv, acc[nf], 0, 0, 0);
            }
        }
    }

    // ---- epilogue: bias + bf16 store to aT[b][h/8][w][h%8] ----
    const int b1 = m0 >> 8;
#pragma unroll
    for (int nf = 0; nf < 4; ++nf) {
        const int h    = n0 + nf * 16 + l15;
        const float bv = lin_b[h];
        const long hbase = ((long)(b1 * 96 + (h >> 3)) * 256) * 8 + (h & 7);
#pragma unroll
        for (int i = 0; i < 4; ++i) {
            const int w = (m0 & 255) + wv * 16 + l4 * 4 + i;
            aT[hbase + (long)w * 8] = f2bf(acc[nf][i] + bv);
        }
    }
}

// ---------------------------------------------------------------------------
// kB: merged u-GEMM + bucket-softmax + output, T_l=32 (4x less aT redundancy:
// 98 MB -> 24.6 MB; R10 showed kB is BW-bound on redundant aT reads and
// XCD-swizzle alone couldn't convert them to L2 hits).
// 64 blocks x 512 thr: block = (b, 32 l-rows, full 256 w). 8 waves x 32 w;
// 2 m-frags x 2 n-frags, 96 MFMAs, coalesced 16B B-loads, no k-loop barriers.
// Bucket reduce in LDS, direct fused output (32 rows x 768).
// ---------------------------------------------------------------------------
__global__ __launch_bounds__(512, 1) void kB_attn_out(
    const float* __restrict__ hidden,   // [4][512][768] f32
    const int*   __restrict__ label,    // [4][512][256]
    const short* __restrict__ aT,       // [4][96][256][8] bf16
    const float* __restrict__ emb_c,    // [6][768]
    float*       __restrict__ out)      // [2048][768]
{
    __shared__ short hid[32 * 776];          // 49.7 KB
    __shared__ float s_lds[8][2][16][5];     // 5.1 KB
    __shared__ float s_fin[32][5];
    __shared__ float invd[32];

    const int t = threadIdx.x, lane = t & 63, wv = t >> 6;   // wv 0..7
    const int l15 = lane & 15, l4 = lane >> 4;

    // 64 blocks = 4b x 16j; same-b blocks on 2 XCDs (xcd = id&7 heuristic,
    // harmless if mapping differs). Bijective on [0,64).
    const int i_hw = blockIdx.x;
    const int xcd  = i_hw & 7;
    const int b    = xcd >> 1;
    const int j    = ((xcd & 1) << 3) | (i_hw >> 3);
    const int row0 = b * 512 + j * 32;       // flat (b*512 + l) base

    // ---- stage 32 hidden rows -> bf16 LDS ----
    {
        const float* hrow = hidden + (long)row0 * HH;
#pragma unroll
        for (int jj = 0; jj < 6; ++jj) {
            const int ci  = t + jj * 512;        // 0..3071 (32 rows x 96 chunks)
            const int row = ci / 96;
            const int col = (ci - row * 96) * 8;
            const float4 p0 = *(const float4*)(hrow + (long)row * HH + col);
            const float4 p1 = *(const float4*)(hrow + (long)row * HH + col + 4);
            bf16x8 v;
            v[0] = f2bf(p0.x); v[1] = f2bf(p0.y); v[2] = f2bf(p0.z); v[3] = f2bf(p0.w);
            v[4] = f2bf(p1.x); v[5] = f2bf(p1.y); v[6] = f2bf(p1.z); v[7] = f2bf(p1.w);
            *(bf16x8*)(&hid[row * 776 + col]) = v;
        }
    }

    // ---- preload labels: lv[nf][mf][i], row = mf*16 + l4*4 + i ----
    int lv[2][2][4];
#pragma unroll
    for (int nf = 0; nf < 2; ++nf) {
        const int w = wv * 32 + nf * 16 + l15;
#pragma unroll
        for (int mf = 0; mf < 2; ++mf)
#pragma unroll
            for (int i = 0; i < 4; ++i) {
                const int row = mf * 16 + l4 * 4 + i;
                lv[nf][mf][i] = label[((long)row0 + row) * WW + w];
            }
    }
    __syncthreads();

    // ---- u GEMM: 24 k-steps, 4 MFMAs each, no barriers ----
    const short* abase = aT + (long)b * 96 * 256 * 8;
    f32x4 acc[2][2] = {};
#pragma unroll
    for (int ks = 0; ks < 24; ++ks) {
        const bf16x8 af0 = *(const bf16x8*)(&hid[l15 * 776 + ks * 32 + l4 * 8]);
        const bf16x8 af1 = *(const bf16x8*)(&hid[(16 + l15) * 776 + ks * 32 + l4 * 8]);
#pragma unroll
        for (int nf = 0; nf < 2; ++nf) {
            const int w = wv * 32 + nf * 16 + l15;
            const bf16x8 bfv =
                *(const bf16x8*)(abase + ((long)(ks * 4 + l4) * 256 + w) * 8);
            acc[0][nf] = __builtin_amdgcn_mfma_f32_16x16x32_bf16(af0, bfv, acc[0][nf], 0, 0, 0);
            acc[1][nf] = __builtin_amdgcn_mfma_f32_16x16x32_bf16(af1, bfv, acc[1][nf], 0, 0, 0);
        }
    }

    // ---- exp + masked label-bucket accumulation ----
    const float inv_temper = 0.03608439182435161f;   // 1/sqrt(768)
    float s_loc[2][4][5];                            // [mf][i][c]
#pragma unroll
    for (int mf = 0; mf < 2; ++mf)
#pragma unroll
        for (int i = 0; i < 4; ++i)
#pragma unroll
            for (int c = 0; c < 5; ++c) s_loc[mf][i][c] = 0.f;
#pragma unroll
    for (int nf = 0; nf < 2; ++nf)
#pragma unroll
        for (int mf = 0; mf < 2; ++mf)
#pragma unroll
            for (int i = 0; i < 4; ++i) {
                const float e = __expf(acc[mf][nf][i] * inv_temper);
#pragma unroll
                for (int c = 1; c <= 5; ++c)
                    s_loc[mf][i][c - 1] += (lv[nf][mf][i] == c) ? e : 0.f;
            }
    // reduce across the 16 lanes (w) sharing the same l4 group
#pragma unroll
    for (int mf = 0; mf < 2; ++mf)
#pragma unroll
        for (int i = 0; i < 4; ++i)
#pragma unroll
            for (int c = 0; c < 5; ++c) {
                float v = s_loc[mf][i][c];
                v += __shfl_xor(v, 1);
                v += __shfl_xor(v, 2);
                v += __shfl_xor(v, 4);
                v += __shfl_xor(v, 8);
                s_loc[mf][i][c] = v;
            }
    if (l15 == 0) {
#pragma unroll
        for (int mf = 0; mf < 2; ++mf)
#pragma unroll
            for (int i = 0; i < 4; ++i)
#pragma unroll
                for (int c = 0; c < 5; ++c)
                    s_lds[wv][mf][l4 * 4 + i][c] = s_loc[mf][i][c];
    }
    __syncthreads();
    if (t < 32) {       // t = row: mf = t>>4, r16 = t&15
        float den = 1e-10f;
#pragma unroll
        for (int c = 0; c < 5; ++c) {
            float s = 0.f;
#pragma unroll
            for (int q = 0; q < 8; ++q) s += s_lds[q][t >> 4][t & 15][c];
            s_fin[t][c] = s;
            den += s;
        }
        invd[t] = 1.0f / den;
    }
    __syncthreads();

    // ---- fused output: o[row][h] = invd * sum_c s_c * emb_c[c][h] ----
    float ecv0[5], ecv1[5];
#pragma unroll
    for (int c = 0; c < 5; ++c) {
        ecv0[c] = emb_c[(c + 1) * HH + t];
        ecv1[c] = (t < 256) ? emb_c[(c + 1) * HH + 512 + t] : 0.f;
    }

    float* obase = out + (long)row0 * HH;
#pragma unroll
    for (int r = 0; r < 32; ++r) {
        const float id = invd[r];
        const float s0 = s_fin[r][0], s1 = s_fin[r][1], s2 = s_fin[r][2],
                    s3 = s_fin[r][3], s4 = s_fin[r][4];
        {
            const float v = s0 * ecv0[0] + s1 * ecv0[1] + s2 * ecv0[2] +
                            s3 * ecv0[3] + s4 * ecv0[4];
            obase[(long)r * HH + t] = v * id;
        }
        if (t < 256) {
            const float v = s0 * ecv1[0] + s1 * ecv1[1] + s2 * ecv1[2] +
                            s3 * ecv1[3] + s4 * ecv1[4];
            obase[(long)r * HH + 512 + t] = v * id;
        }
    }
}

extern "C" void kernel_launch(void* const* d_in, const int* in_sizes, int n_in,
                              void* d_out, int out_size, void* d_ws, size_t ws_size,
                              hipStream_t stream) {
    const int*   word_seq = (const int*)  d_in[0];
    const float* hidden   = (const float*)d_in[1];
    const int*   label    = (const int*)  d_in[2];
    const float* emb_a    = (const float*)d_in[3];
    const float* lin_w    = (const float*)d_in[4];
    const float* lin_b    = (const float*)d_in[5];
    const float* emb_c    = (const float*)d_in[6];
    float* out = (float*)d_out;

    short* aT = (short*)d_ws;   // 4*96*256*8 shorts = 1.5 MB

    kA_a_gemm<<<dim3(192), 256, 0, stream>>>(word_seq, emb_a, lin_w, lin_b, aT);
    kB_attn_out<<<dim3(64), 512, 0, stream>>>(hidden, label, aT, emb_c, out);
}

// Round 12
// 22.832 us; speedup vs baseline: 1.3468x; 1.3468x over previous
//
#include <hip/hip_runtime.h>

// Problem constants
#define BB 4
#define LL 512
#define WW 256
#define WP 264     // padded w-stride for aT: k-chunk stride 264*16B = 4224B,
                   // NOT 4096 -> breaks L2-bank/channel aliasing of the 4KB stride
#define EE 300
#define HH 768

typedef __attribute__((ext_vector_type(8))) short bf16x8;
typedef __attribute__((ext_vector_type(4))) float f32x4;

__device__ __forceinline__ short f2bf(float f) {
    union { float f; unsigned u; } v; v.f = f;
    unsigned r = (v.u + 0x7FFFu + ((v.u >> 16) & 1u)) >> 16;
    return (short)r;
}

// ---------------------------------------------------------------------------
// kA: aT = (emb_a[word_seq] @ lin_w + lin_b), bf16, k-major
// aT[b][h/8][w][h%8] with PADDED w-stride WP=264. (Body = R8/R10, only the
// store index changed.)
// ---------------------------------------------------------------------------
__global__ __launch_bounds__(256, 1) void kA_a_gemm(
    const int*   __restrict__ word_seq,
    const float* __restrict__ emb_a,
    const float* __restrict__ lin_w,
    const float* __restrict__ lin_b,
    short*       __restrict__ aT)      // [4][96][WP][8] bf16
{
    __shared__ short eaL[2][64 * 168];   // [half][m-row][k] bf16, stride 168
    __shared__ short lwL[2][64 * 168];   // [half][n-row(h)][k]

    const int t  = threadIdx.x;
    const int m0 = (blockIdx.x & 15) * 64;
    const int n0 = (blockIdx.x >> 4) * 64;

    const int lane = t & 63, wv = t >> 6;
    const int l15 = lane & 15, l4 = lane >> 4;

    const int r_ea = t >> 2;             // 0..63 m-row
    const int q_ea = t & 3;              // quarter of the 160-wide half
    const int h_lw = t & 63;             // n-row
    const int q_lw = t >> 6;             // quarter

    const int    wrow = word_seq[m0 + r_ea];
    const float* arow = emb_a + (long)wrow * EE;

    f32x4 acc[4] = {};
    float ea_reg[40], lw_reg[40];

#pragma unroll
    for (int half = 0; half < 2; ++half) {
        const int k0 = half * 160;
        // ---- issue this half's loads (all independent) ----
        {
            const int cbase = k0 + q_ea * 40;
#pragma unroll
            for (int c4 = 0; c4 < 10; ++c4) {
                const int col = cbase + c4 * 4;
                if (col <= 296) {        // full float4 real (E=300, col%4==0)
                    const float4 p = *(const float4*)(arow + col);
                    ea_reg[c4 * 4 + 0] = p.x; ea_reg[c4 * 4 + 1] = p.y;
                    ea_reg[c4 * 4 + 2] = p.z; ea_reg[c4 * 4 + 3] = p.w;
                } else {
                    ea_reg[c4 * 4 + 0] = 0.f; ea_reg[c4 * 4 + 1] = 0.f;
                    ea_reg[c4 * 4 + 2] = 0.f; ea_reg[c4 * 4 + 3] = 0.f;
                }
            }
            const int cb2 = k0 + q_lw * 40;
#pragma unroll
            for (int j = 0; j < 40; ++j) {
                const int col = cb2 + j;
                lw_reg[j] = (col < EE) ? lin_w[(long)col * HH + n0 + h_lw] : 0.f;
            }
        }
        // ---- pack to LDS ----
        {
            const int eoff = r_ea * 168 + q_ea * 40;
#pragma unroll
            for (int c8 = 0; c8 < 5; ++c8) {
                bf16x8 sv;
#pragma unroll
                for (int j = 0; j < 8; ++j) sv[j] = f2bf(ea_reg[c8 * 8 + j]);
                *(bf16x8*)(&eaL[half][eoff + c8 * 8]) = sv;
            }
            const int loff = h_lw * 168 + q_lw * 40;
#pragma unroll
            for (int c8 = 0; c8 < 5; ++c8) {
                bf16x8 sv;
#pragma unroll
                for (int j = 0; j < 8; ++j) sv[j] = f2bf(lw_reg[c8 * 8 + j]);
                *(bf16x8*)(&lwL[half][loff + c8 * 8]) = sv;
            }
        }
        __syncthreads();
        // ---- MFMA on this half (5 k-steps x 4 n-frags) ----
#pragma unroll
        for (int ks = 0; ks < 5; ++ks) {
            const bf16x8 af =
                *(const bf16x8*)(&eaL[half][(wv * 16 + l15) * 168 + ks * 32 + l4 * 8]);
#pragma unroll
            for (int nf = 0; nf < 4; ++nf) {
                const bf16x8 bfv =
                    *(const bf16x8*)(&lwL[half][(nf * 16 + l15) * 168 + ks * 32 + l4 * 8]);
                acc[nf] = __builtin_amdgcn_mfma_f32_16x16x32_bf16(af, bfv, acc[nf], 0, 0, 0);
            }
        }
    }

    // ---- epilogue: bias + bf16 store to aT[b][h/8][w][h%8], w-stride WP ----
    const int b1 = m0 >> 8;
#pragma unroll
    for (int nf = 0; nf < 4; ++nf) {
        const int h    = n0 + nf * 16 + l15;
        const float bv = lin_b[h];
        const long hbase = ((long)(b1 * 96 + (h >> 3)) * WP) * 8 + (h & 7);
#pragma unroll
        for (int i = 0; i < 4; ++i) {
            const int w = (m0 & 255) + wv * 16 + l4 * 4 + i;
            aT[hbase + (long)w * 8] = f2bf(acc[nf][i] + bv);
        }
    }
}

// ---------------------------------------------------------------------------
// kB: merged u-GEMM + bucket-softmax + output. EXACT R10 body; only the aT
// load index uses the padded stride WP (k-chunk stride 4224B, de-aliased).
// 256 blocks x 512 thr, block = (b, 8 l-rows, full 256 w), XCD swizzle.
// ---------------------------------------------------------------------------
__global__ __launch_bounds__(512) void kB_attn_out(
    const float* __restrict__ hidden,   // [4][512][768] f32
    const int*   __restrict__ label,    // [4][512][256]
    const short* __restrict__ aT,       // [4][96][WP][8] bf16
    const float* __restrict__ emb_c,    // [6][768]
    float*       __restrict__ out)      // [2048][768]
{
    __shared__ short hid[16 * 776];
    __shared__ float s_lds[8][16][5];
    __shared__ float s_fin[8][5];
    __shared__ float invd[8];

    const int t = threadIdx.x, lane = t & 63, wv = t >> 6;   // wv 0..7
    const int l15 = lane & 15, l4 = lane >> 4;

    // XCD-aware swizzle: xcd = i&7 (round-robin), b = xcd/2,
    // j = (i&1)*32 + (i>>3) in [0,64). Bijective on [0,256).
    const int i_hw = blockIdx.x;
    const int b    = (i_hw & 7) >> 1;
    const int j    = ((i_hw & 1) << 5) + (i_hw >> 3);
    const int row0 = b * 512 + j * 8;       // flat (b*512 + l) base

    // ---- stage 8 hidden rows -> bf16 LDS; rows 8..15 zero ----
    {
        const float* hrow = hidden + (long)row0 * HH;
        const bf16x8 z = {};
#pragma unroll
        for (int jj = 0; jj < 2; ++jj) {
            const int ci = t + jj * 512;         // 16B chunk id, guard < 768
            if (ci < 768) {
                const int row = ci / 96;         // 96 chunks per row
                const int col = (ci - row * 96) * 8;
                const float4 p0 = *(const float4*)(hrow + (long)row * HH + col);
                const float4 p1 = *(const float4*)(hrow + (long)row * HH + col + 4);
                bf16x8 v;
                v[0] = f2bf(p0.x); v[1] = f2bf(p0.y); v[2] = f2bf(p0.z); v[3] = f2bf(p0.w);
                v[4] = f2bf(p1.x); v[5] = f2bf(p1.y); v[6] = f2bf(p1.z); v[7] = f2bf(p1.w);
                *(bf16x8*)(&hid[row * 776 + col]) = v;
                *(bf16x8*)(&hid[(8 + row) * 776 + col]) = z;
            }
        }
    }

    // ---- preload labels for this thread's (row, w) pairs ----
    int lv[2][4];
#pragma unroll
    for (int nf = 0; nf < 2; ++nf) {
        const int w = wv * 32 + nf * 16 + l15;
#pragma unroll
        for (int ii = 0; ii < 4; ++ii) {
            const int row = l4 * 4 + ii;         // 0..15; real if < 8
            lv[nf][ii] = (row < 8) ? label[((long)row0 + row) * WW + w] : 0;
        }
    }
    __syncthreads();

    // ---- u GEMM: 24 k-steps, no barriers ----
    const short* abase = aT + (long)b * 96 * WP * 8;
    f32x4 acc[2] = {};
#pragma unroll
    for (int ks = 0; ks < 24; ++ks) {
        const bf16x8 af = *(const bf16x8*)(&hid[l15 * 776 + ks * 32 + l4 * 8]);
#pragma unroll
        for (int nf = 0; nf < 2; ++nf) {
            const int w = wv * 32 + nf * 16 + l15;
            const bf16x8 bfv =
                *(const bf16x8*)(abase + ((long)(ks * 4 + l4) * WP + w) * 8);
            acc[nf] = __builtin_amdgcn_mfma_f32_16x16x32_bf16(af, bfv, acc[nf], 0, 0, 0);
        }
    }

    // ---- exp + masked label-bucket accumulation ----
    const float inv_temper = 0.03608439182435161f;   // 1/sqrt(768)
    float s_loc[4][5];
#pragma unroll
    for (int ii = 0; ii < 4; ++ii)
#pragma unroll
        for (int c = 0; c < 5; ++c) s_loc[ii][c] = 0.f;
#pragma unroll
    for (int nf = 0; nf < 2; ++nf) {
#pragma unroll
        for (int ii = 0; ii < 4; ++ii) {
            const float e = __expf(acc[nf][ii] * inv_temper);
#pragma unroll
            for (int c = 1; c <= 5; ++c)
                s_loc[ii][c - 1] += (lv[nf][ii] == c) ? e : 0.f;
        }
    }
    // reduce across the 16 lanes (w) sharing the same l4 group
#pragma unroll
    for (int ii = 0; ii < 4; ++ii) {
#pragma unroll
        for (int c = 0; c < 5; ++c) {
            float v = s_loc[ii][c];
            v += __shfl_xor(v, 1);
            v += __shfl_xor(v, 2);
            v += __shfl_xor(v, 4);
            v += __shfl_xor(v, 8);
            s_loc[ii][c] = v;
        }
    }
    if (l15 == 0) {
#pragma unroll
        for (int ii = 0; ii < 4; ++ii)
#pragma unroll
            for (int c = 0; c < 5; ++c)
                s_lds[wv][l4 * 4 + ii][c] = s_loc[ii][c];
    }
    __syncthreads();
    if (t < 8) {
        float den = 1e-10f;
#pragma unroll
        for (int c = 0; c < 5; ++c) {
            float s = 0.f;
#pragma unroll
            for (int q = 0; q < 8; ++q) s += s_lds[q][t][c];
            s_fin[t][c] = s;
            den += s;
        }
        invd[t] = 1.0f / den;
    }
    __syncthreads();

    // ---- fused output: o[row][h] = invd * sum_c s_c * emb_c[c][h] ----
    float ecv0[5], ecv1[5];
#pragma unroll
    for (int c = 0; c < 5; ++c) {
        ecv0[c] = emb_c[(c + 1) * HH + t];
        ecv1[c] = (t < 256) ? emb_c[(c + 1) * HH + 512 + t] : 0.f;
    }

    float* obase = out + (long)row0 * HH;
#pragma unroll
    for (int r = 0; r < 8; ++r) {
        const float id = invd[r];
        const float s0 = s_fin[r][0], s1 = s_fin[r][1], s2 = s_fin[r][2],
                    s3 = s_fin[r][3], s4 = s_fin[r][4];
        {
            const float v = s0 * ecv0[0] + s1 * ecv0[1] + s2 * ecv0[2] +
                            s3 * ecv0[3] + s4 * ecv0[4];
            obase[(long)r * HH + t] = v * id;
        }
        if (t < 256) {
            const float v = s0 * ecv1[0] + s1 * ecv1[1] + s2 * ecv1[2] +
                            s3 * ecv1[3] + s4 * ecv1[4];
            obase[(long)r * HH + 512 + t] = v * id;
        }
    }
}

extern "C" void kernel_launch(void* const* d_in, const int* in_sizes, int n_in,
                              void* d_out, int out_size, void* d_ws, size_t ws_size,
                              hipStream_t stream) {
    const int*   word_seq = (const int*)  d_in[0];
    const float* hidden   = (const float*)d_in[1];
    const int*   label    = (const int*)  d_in[2];
    const float* emb_a    = (const float*)d_in[3];
    const float* lin_w    = (const float*)d_in[4];
    const float* lin_b    = (const float*)d_in[5];
    const float* emb_c    = (const float*)d_in[6];
    float* out = (float*)d_out;

    short* aT = (short*)d_ws;   // 4*96*264*8 shorts = 1.62 MB

    kA_a_gemm<<<dim3(192), 256, 0, stream>>>(word_seq, emb_a, lin_w, lin_b, aT);
    kB_attn_out<<<dim3(256), 512, 0, stream>>>(hidden, label, aT, emb_c, out);
}